// Round 15
// baseline (130.309 us; speedup 1.0000x reference)
//
#include <hip/hip_runtime.h>

typedef unsigned char u8;
typedef float f32x4 __attribute__((ext_vector_type(4)));
typedef int i32x4 __attribute__((ext_vector_type(4)));
typedef int i32x8 __attribute__((ext_vector_type(8)));

#define NROWS 16384
#define DIM 128

// exp(-2*sim) = exp2(sim * -2*log2(e)); scale folded into normalized B rows.
#define NEG2LOG2E -2.8853900817779268f
#define SCALE ((float)(1.0 / (16384.0 * 16383.0)))

// E8M0 scale byte 127 = 2^0 = 1.0, replicated.
#define SCALE1 0x7F7F7F7F

#define KMAX 320
#define NGEMM 4096

// Block l (of 100): scan labels, compute own offset (= #rows with label<l),
// compact this label's row indices (order within label irrelevant — the
// total pair-sum is permutation-invariant). Emits rowSrc (sorted->orig) and
// sLab (sorted labels).
__global__ __launch_bounds__(256) void sort_kernel(
    const int* __restrict__ labels, int* __restrict__ rowSrc,
    int* __restrict__ sLab)
{
    __shared__ int sIdx[KMAX];
    __shared__ int sCnt, sLt;
    int l   = blockIdx.x;
    int tid = threadIdx.x;
    int lane = tid & 63;
    if (tid == 0) { sCnt = 0; sLt = 0; }
    __syncthreads();

    int lt = 0;
    for (int i = tid; i < NROWS; i += 256) {
        int lab = labels[i];
        if (lab == l) {
            int p = atomicAdd(&sCnt, 1);
            if (p < KMAX) sIdx[p] = i;
        } else if (lab < l) lt++;
    }
    #pragma unroll
    for (int off = 32; off; off >>= 1) lt += __shfl_xor(lt, off, 64);
    if (lane == 0) atomicAdd(&sLt, lt);
    __syncthreads();

    int off = sLt;
    int k = sCnt < KMAX ? sCnt : KMAX;
    for (int j = tid; j < k; j += 256) {
        rowSrc[off + j] = sIdx[j];
        sLab[off + j] = l;
    }
}

// Two rows per wave (half-wave per row), rows GATHERED via rowSrc so output
// is label-sorted. float4 loads, half-wave shuffle reduction, paired
// cvt_pk_fp8 -> one dword store per lane (fully coalesced stores).
// B rows pre-scaled by -2*log2(e) so GEMM output feeds exp2 directly.
__global__ __launch_bounds__(256) void norm_kernel(
    const float* __restrict__ a, const float* __restrict__ b,
    const int* __restrict__ rowSrc,
    u8* __restrict__ aO, u8* __restrict__ bO)
{
    int tid  = threadIdx.x;
    int lane = tid & 63;
    int w    = tid >> 6;
    int half = lane >> 5;
    int l32  = lane & 31;
    long row = (long)blockIdx.x * 8 + w * 2 + half;
    long src = rowSrc[row];

    const float4 va = ((const float4*)(a + src * DIM))[l32];
    float sa = va.x * va.x + va.y * va.y + va.z * va.z + va.w * va.w;
    #pragma unroll
    for (int off = 16; off; off >>= 1) sa += __shfl_xor(sa, off, 64);
    float inva = 1.0f / fmaxf(sqrtf(sa), 1e-12f);
    int pa = __builtin_amdgcn_cvt_pk_fp8_f32(va.x * inva, va.y * inva, 0, false);
    pa = __builtin_amdgcn_cvt_pk_fp8_f32(va.z * inva, va.w * inva, pa, true);
    ((int*)(aO + row * DIM))[l32] = pa;

    const float4 vb = ((const float4*)(b + src * DIM))[l32];
    float sb = vb.x * vb.x + vb.y * vb.y + vb.z * vb.z + vb.w * vb.w;
    #pragma unroll
    for (int off = 16; off; off >>= 1) sb += __shfl_xor(sb, off, 64);
    float invb = NEG2LOG2E / fmaxf(sqrtf(sb), 1e-12f);
    int pb = __builtin_amdgcn_cvt_pk_fp8_f32(vb.x * invb, vb.y * invb, 0, false);
    pb = __builtin_amdgcn_cvt_pk_fp8_f32(vb.z * invb, vb.w * invb, pb, true);
    ((int*)(bO + row * DIM))[l32] = pb;
}

// 4096 blocks, each 128 rows x 512 cols = 4 column-tiles of 128x128 over the
// LABEL-SORTED fp8 arrays. Because rows are sorted by label, a tile contains
// same-label pairs only if its row-strip and col-tile label ranges intersect
// (~2% of tiles, near the diagonal): those use the masked epilogue; all
// others run maskless (exp2+add only). Exact by construction — no
// correction pass (R8-R14's corr cost ~10 us of co-residency tax).
// A tile (16 KB) staged once, A-operands register-resident; B double-
// buffered (2 x 16 KB), global_load_lds w/ granule-xor swizzle; MX-scaled
// fp8 MFMA 16x16x128 (scale=1.0), one instr per (mi,ni) covers K=128.
__global__ __launch_bounds__(256, 3) void gemm_kernel(
    const u8* __restrict__ A, const u8* __restrict__ B,
    const int* __restrict__ sLab, float* __restrict__ partials)
{
    __shared__ u8 sA[16384];
    __shared__ u8 sB[2][16384];

    int tid  = threadIdx.x;
    int lane = tid & 63;
    int w    = tid >> 6;
    int mrow = lane & 15;
    int q    = lane >> 4;
    int wr = w >> 1;
    int wc = w & 1;

    const f32x4 FZERO = (f32x4){0.f, 0.f, 0.f, 0.f};

    int g  = blockIdx.x;
    int rowBase = (g >> 5) * 128;
    int colBase = (g & 31) * 512;

    // Staging pattern: LDS granule g of row m holds global granule g^(m&7).
    int m0 = tid >> 3;
    int p0 = tid & 7;
    int srcOff = m0 * 128 + ((p0 ^ (m0 & 7)) << 4);
    int ldsOff = (tid - lane) * 16;      // wave-uniform base

    const u8* gA = A + (size_t)rowBase * DIM + srcOff;
    const u8* gB = B + (size_t)colBase * DIM + srcOff;

    {
        const u8* gpA = gA;
        const u8* gpB = gB;
        u8* lpA = &sA[ldsOff];
        u8* lpB = &sB[0][ldsOff];
        #pragma unroll
        for (int it = 0; it < 4; it++) {
            __builtin_amdgcn_global_load_lds(
                (const __attribute__((address_space(1))) void*)gpA,
                (__attribute__((address_space(3))) void*)lpA, 16, 0, 0);
            __builtin_amdgcn_global_load_lds(
                (const __attribute__((address_space(1))) void*)gpB,
                (__attribute__((address_space(3))) void*)lpB, 16, 0, 0);
            gpA += 4096; gpB += 4096; lpA += 4096; lpB += 4096;
        }
    }

    // Row-strip label range (sorted -> just the two ends).
    int labRowLo = sLab[rowBase];
    int labRowHi = sLab[rowBase + 127];

    // Fragment LDS byte offsets: low granule (2q)^(row&7); high = ^16.
    int aOff[4], bOff[4];
    #pragma unroll
    for (int mi = 0; mi < 4; mi++) {
        int m = wr * 64 + mi * 16 + mrow;
        aOff[mi] = m * 128 + (((q << 1) ^ (m & 7)) << 4);
        int n = wc * 64 + mi * 16 + mrow;
        bOff[mi] = n * 128 + (((q << 1) ^ (n & 7)) << 4);
    }

    __syncthreads();   // A + B0 resident

    // A operands register-resident for all 4 tiles (32 VGPRs).
    i32x8 a8[4];
    #pragma unroll
    for (int mi = 0; mi < 4; mi++) {
        *((i32x4*)&a8[mi])     = *(const i32x4*)(sA + aOff[mi]);
        *((i32x4*)&a8[mi] + 1) = *(const i32x4*)(sA + (aOff[mi] ^ 16));
    }

    float s = 0.0f;

    #pragma unroll
    for (int jt = 0; jt < 4; jt++) {
        if (jt < 3) {
            const u8* gp = gB + (jt + 1) * (128 * DIM);
            u8* lp = &sB[(jt + 1) & 1][ldsOff];
            #pragma unroll
            for (int it = 0; it < 4; it++) {
                __builtin_amdgcn_global_load_lds(
                    (const __attribute__((address_space(1))) void*)gp,
                    (__attribute__((address_space(3))) void*)lp, 16, 0, 0);
                gp += 4096; lp += 4096;
            }
        }

        const u8* sb = sB[jt & 1];
        i32x8 b8[4];
        #pragma unroll
        for (int ni = 0; ni < 4; ni++) {
            *((i32x4*)&b8[ni])     = *(const i32x4*)(sb + bOff[ni]);
            *((i32x4*)&b8[ni] + 1) = *(const i32x4*)(sb + (bOff[ni] ^ 16));
        }

        // One MX-MFMA per (mi,ni), C = shared zero.
        f32x4 acc[4][4];
        #pragma unroll
        for (int mi = 0; mi < 4; mi++)
            #pragma unroll
            for (int ni = 0; ni < 4; ni++)
                acc[mi][ni] = __builtin_amdgcn_mfma_scale_f32_16x16x128_f8f6f4(
                    a8[mi], b8[ni], FZERO, 0, 0, 0, SCALE1, 0, SCALE1);

        // Does this 128x128 tile contain same-label pairs? (block-uniform)
        int c0 = colBase + jt * 128;
        int labColLo = sLab[c0];
        int labColHi = sLab[c0 + 127];
        bool overlap = (labRowLo <= labColHi) && (labColLo <= labRowHi);

        float s0 = 0.0f, s1 = 0.0f;
        if (!overlap) {
            // Maskless epilogue: exp2 + add only (98% of tiles).
            #pragma unroll
            for (int mi = 0; mi < 4; mi++)
                #pragma unroll
                for (int ni = 0; ni < 4; ni++)
                    #pragma unroll
                    for (int r = 0; r < 4; r++) {
                        float e = __builtin_amdgcn_exp2f(acc[mi][ni][r]);
                        if (r & 1) s1 += e; else s0 += e;
                    }
        } else {
            // Masked epilogue for diagonal tiles (~2%).
            int iBase = rowBase + wr * 64 + q * 4;
            int jBase = c0 + wc * 64 + mrow;
            int li[16], lj[4];
            #pragma unroll
            for (int mi = 0; mi < 4; mi++)
                #pragma unroll
                for (int r = 0; r < 4; r++)
                    li[mi * 4 + r] = sLab[iBase + mi * 16 + r];
            #pragma unroll
            for (int ni = 0; ni < 4; ni++)
                lj[ni] = sLab[jBase + ni * 16];
            #pragma unroll
            for (int mi = 0; mi < 4; mi++)
                #pragma unroll
                for (int ni = 0; ni < 4; ni++)
                    #pragma unroll
                    for (int r = 0; r < 4; r++) {
                        float e = __builtin_amdgcn_exp2f(acc[mi][ni][r]);
                        float m = (li[mi * 4 + r] != lj[ni]) ? e : 0.0f;
                        if (r & 1) s1 += m; else s0 += m;
                    }
        }
        s += s0 + s1;

        __syncthreads();
    }

    #pragma unroll
    for (int off = 32; off; off >>= 1) s += __shfl_xor(s, off, 64);

    float* red = (float*)sA;
    if (lane == 0) red[w] = s;
    __syncthreads();
    if (tid == 0) {
        float t = (red[0] + red[1]) + (red[2] + red[3]);
        partials[g] = t * SCALE;
    }
}

__global__ __launch_bounds__(256) void reduce_kernel(
    const float* __restrict__ gP, float* __restrict__ out)
{
    int tid = threadIdx.x;
    const float4* p4 = (const float4*)gP;
    float s = 0.0f;
    #pragma unroll 4
    for (int i = tid; i < 1024; i += 256) {
        float4 v = p4[i];
        s += (v.x + v.y) + (v.z + v.w);
    }
    #pragma unroll
    for (int off = 32; off; off >>= 1) s += __shfl_xor(s, off, 64);
    __shared__ float red[4];
    if ((tid & 63) == 0) red[tid >> 6] = s;
    __syncthreads();
    if (tid == 0) out[0] = (red[0] + red[1]) + (red[2] + red[3]);
}

extern "C" void kernel_launch(void* const* d_in, const int* in_sizes, int n_in,
                              void* d_out, int out_size, void* d_ws, size_t ws_size,
                              hipStream_t stream) {
    const float* self_p = (const float*)d_in[0];
    const float* pos_p  = (const float*)d_in[1];
    const int*   labels = (const int*)d_in[2];
    float* out = (float*)d_out;

    u8* aB = (u8*)d_ws;                         // 2 MB fp8 normalized self (sorted)
    u8* bB = aB + (size_t)NROWS * DIM;          // 2 MB fp8 normalized pos (sorted, pre-scaled)
    float* gemmP = (float*)(bB + (size_t)NROWS * DIM);     // 16 KB
    int* rowSrc  = (int*)(gemmP + NGEMM);                   // 64 KB
    int* sLab    = rowSrc + NROWS;                          // 64 KB

    sort_kernel<<<100, 256, 0, stream>>>(labels, rowSrc, sLab);
    norm_kernel<<<NROWS / 8, 256, 0, stream>>>(self_p, pos_p, rowSrc, aB, bB);
    gemm_kernel<<<NGEMM, 256, 0, stream>>>(aB, bB, sLab, gemmP);
    reduce_kernel<<<1, 256, 0, stream>>>(gemmP, out);
}